// Round 8
// baseline (210.521 us; speedup 1.0000x reference)
//
#include <hip/hip_runtime.h>
#include <hip/hip_bf16.h>

typedef __attribute__((ext_vector_type(8))) short short8;
typedef __attribute__((ext_vector_type(4))) short short4v;
typedef __attribute__((ext_vector_type(4))) float f32x4;

#define TT 4096
#define DM 1024
#define NH 16
#define NPROJ 1280   // 128 qs + 128 ks + 256 qg + 256 kg + 512 v
#define DATTN 512

static __device__ __forceinline__ short f2bf(float f) {
  __hip_bfloat16 h = __float2bfloat16(f);
  return *reinterpret_cast<short*>(&h);
}
static __device__ __forceinline__ float bf2f(__hip_bfloat16 h) { return __bfloat162float(h); }
static __device__ __forceinline__ unsigned pk2(float a, float b) {
  float2 t; t.x = a; t.y = b;
  __hip_bfloat162 r = __float22bfloat162_rn(t);
  return *reinterpret_cast<unsigned*>(&r);
}

// ---------------- fp32 -> bf16 convert (x, out_w) ----------------
__global__ __launch_bounds__(256) void k_f32_to_bf16(const float* __restrict__ in,
                                                     __hip_bfloat16* __restrict__ out, int n4) {
  int i = blockIdx.x * blockDim.x + threadIdx.x;
  if (i >= n4) return;
  float4 v = reinterpret_cast<const float4*>(in)[i];
  short4v o;
  o[0] = f2bf(v.x); o[1] = f2bf(v.y); o[2] = f2bf(v.z); o[3] = f2bf(v.w);
  reinterpret_cast<short4v*>(out)[i] = o;
}

// ---------------- concat 5 weight matrices into (1280,1024) bf16 ----------------
__global__ __launch_bounds__(256) void k_pack_wcat(const float* __restrict__ qs,
    const float* __restrict__ ks, const float* __restrict__ qg, const float* __restrict__ kg,
    const float* __restrict__ vw, __hip_bfloat16* __restrict__ w, int n4) {
  int i = blockIdx.x * blockDim.x + threadIdx.x;
  if (i >= n4) return;
  int idx = i * 4;
  int row = idx >> 10;
  int col = idx & 1023;
  const float* src;
  if (row < 128)      src = qs + (size_t)row * DM;
  else if (row < 256) src = ks + (size_t)(row - 128) * DM;
  else if (row < 512) src = qg + (size_t)(row - 256) * DM;
  else if (row < 768) src = kg + (size_t)(row - 512) * DM;
  else                src = vw + (size_t)(row - 768) * DM;
  float4 v = *reinterpret_cast<const float4*>(src + col);
  short4v o;
  o[0] = f2bf(v.x); o[1] = f2bf(v.y); o[2] = f2bf(v.z); o[3] = f2bf(v.w);
  *reinterpret_cast<short4v*>(w + idx) = o;
}

// ---------------- bf16 GEMM, B^T layout: C[m][n] = sum_k A[m][k]*B[n][k] ----------------
template<int OUT_BF16>
__global__ __launch_bounds__(256) void k_gemm_bt(const __hip_bfloat16* __restrict__ A,
    const __hip_bfloat16* __restrict__ B, void* __restrict__ Cv, int M, int N, int K) {
  __shared__ alignas(16) __hip_bfloat16 lA[128 * 32];
  __shared__ alignas(16) __hip_bfloat16 lB[128 * 32];
  const int tid = threadIdx.x;
  const int lane = tid & 63;
  const int wid = tid >> 6;
  const int m0 = blockIdx.x * 128, n0 = blockIdx.y * 128;
  const int wm = (wid >> 1) * 64, wn = (wid & 1) * 64;
  const int srow = tid >> 2;          // 0..63
  const int scol = (tid & 3) * 8;     // bf16 elements
  const int fr = lane & 15, fk = (lane >> 4) * 8;
  f32x4 acc[4][4];
  const f32x4 zz = {0.f, 0.f, 0.f, 0.f};
#pragma unroll
  for (int m = 0; m < 4; ++m)
#pragma unroll
    for (int n = 0; n < 4; ++n) acc[m][n] = zz;

  for (int kt = 0; kt < K; kt += 32) {
    __syncthreads();
    {
      const __hip_bfloat16* ga0 = A + (size_t)(m0 + srow) * K + kt + scol;
      const __hip_bfloat16* ga1 = A + (size_t)(m0 + 64 + srow) * K + kt + scol;
      const __hip_bfloat16* gb0 = B + (size_t)(n0 + srow) * K + kt + scol;
      const __hip_bfloat16* gb1 = B + (size_t)(n0 + 64 + srow) * K + kt + scol;
      __builtin_amdgcn_global_load_lds((const __attribute__((address_space(1))) void*)ga0,
          (__attribute__((address_space(3))) void*)(lA + srow * 32 + scol), 16, 0, 0);
      __builtin_amdgcn_global_load_lds((const __attribute__((address_space(1))) void*)ga1,
          (__attribute__((address_space(3))) void*)(lA + (64 + srow) * 32 + scol), 16, 0, 0);
      __builtin_amdgcn_global_load_lds((const __attribute__((address_space(1))) void*)gb0,
          (__attribute__((address_space(3))) void*)(lB + srow * 32 + scol), 16, 0, 0);
      __builtin_amdgcn_global_load_lds((const __attribute__((address_space(1))) void*)gb1,
          (__attribute__((address_space(3))) void*)(lB + (64 + srow) * 32 + scol), 16, 0, 0);
    }
    __syncthreads();
    short8 af[4], bfr[4];
#pragma unroll
    for (int m = 0; m < 4; ++m)
      af[m] = *reinterpret_cast<const short8*>(lA + (wm + m * 16 + fr) * 32 + fk);
#pragma unroll
    for (int n = 0; n < 4; ++n)
      bfr[n] = *reinterpret_cast<const short8*>(lB + (wn + n * 16 + fr) * 32 + fk);
#pragma unroll
    for (int m = 0; m < 4; ++m)
#pragma unroll
      for (int n = 0; n < 4; ++n)
        acc[m][n] = __builtin_amdgcn_mfma_f32_16x16x32_bf16(af[m], bfr[n], acc[m][n], 0, 0, 0);
  }
  const int cr = (lane >> 4) * 4, cc = lane & 15;
#pragma unroll
  for (int m = 0; m < 4; ++m)
#pragma unroll
    for (int n = 0; n < 4; ++n)
#pragma unroll
      for (int j = 0; j < 4; ++j) {
        const int row = m0 + wm + m * 16 + cr + j;
        const int col = n0 + wn + n * 16 + cc;
        if (OUT_BF16)
          ((__hip_bfloat16*)Cv)[(size_t)row * N + col] = __float2bfloat16(acc[m][n][j]);
        else
          ((float*)Cv)[(size_t)row * N + col] = acc[m][n][j];
      }
}

// ---------------- RoPE + pack Q/K (H,T,32) and V^T (H,32,T) ----------------
// qscale folds 1/sqrt(24) * exp(logit_scale) * log2(e)  (softmax uses exp2)
__global__ __launch_bounds__(256) void k_rope_pack(const __hip_bfloat16* __restrict__ proj,
    const float* __restrict__ ls, const int* __restrict__ posp,
    __hip_bfloat16* __restrict__ Qp, __hip_bfloat16* __restrict__ Kp,
    __hip_bfloat16* __restrict__ Vt) {
  const int gid = blockIdx.x * blockDim.x + threadIdx.x;  // T*NH, t fastest
  const int t = gid & (TT - 1);
  const int h = gid >> 12;
  const __hip_bfloat16* pr = proj + (size_t)t * NPROJ;
  const float qscale = 0.20412414523193154f * 1.4426950408889634f * __expf(ls[h]);
  const float pos = (float)(t + posp[0]);
  const float invf[8] = {1.0f, 0.31622776601683794f, 0.1f, 0.031622776601683794f,
                         0.01f, 0.0031622776601683794f, 0.001f, 0.00031622776601683794f};
  short8 qv[4], kv[4];
  const short8 z8 = {0, 0, 0, 0, 0, 0, 0, 0};
  qv[3] = z8; kv[3] = z8;
#pragma unroll
  for (int i = 0; i < 8; ++i) {
    qv[0][i] = f2bf(bf2f(pr[h * 8 + i]) * qscale);
    kv[0][i] = f2bf(bf2f(pr[128 + h * 8 + i]));
  }
#pragma unroll
  for (int i = 0; i < 8; ++i) {
    const float ang = pos * invf[i];
    float ss, cc;
    __sincosf(ang, &ss, &cc);
    const float x1q = bf2f(pr[256 + h * 16 + i]), x2q = bf2f(pr[256 + h * 16 + 8 + i]);
    const float x1k = bf2f(pr[512 + h * 16 + i]), x2k = bf2f(pr[512 + h * 16 + 8 + i]);
    qv[1][i] = f2bf((x1q * cc - x2q * ss) * qscale);
    qv[2][i] = f2bf((x1q * ss + x2q * cc) * qscale);
    kv[1][i] = f2bf(x1k * cc - x2k * ss);
    kv[2][i] = f2bf(x1k * ss + x2k * cc);
  }
  short8* qdst = reinterpret_cast<short8*>(Qp + ((size_t)h * TT + t) * 32);
  short8* kdst = reinterpret_cast<short8*>(Kp + ((size_t)h * TT + t) * 32);
#pragma unroll
  for (int p = 0; p < 4; ++p) { qdst[p] = qv[p]; kdst[p] = kv[p]; }
#pragma unroll
  for (int i = 0; i < 32; ++i)
    Vt[((size_t)h * 32 + i) * TT + t] = pr[768 + h * 32 + i];
}

// ---------------- causal flash attention, zero-LDS (register-permuted PV) ----------------
// 2048 blocks x 2 waves (R5 schedule: wave w takes r = sub / 255-sub).
// mfma(K,Q): lane (c,g) owns q-row q0+c; s[ct][j] = P[q=c][kv=ct*16+g*4+j].
// PV uses a bijective K-position permutation pi(8g+m) = (m<4 ? 4g+m : 16+4g+m-4)
// applied to BOTH operands: B-frag = lane's OWN s-values packed to bf16
// (no LDS, no cross-lane); A-frag = V^T loaded as two 8B pieces per k-block.
__global__ __launch_bounds__(128) void k_attn(const __hip_bfloat16* __restrict__ Qp,
    const __hip_bfloat16* __restrict__ Kp, const __hip_bfloat16* __restrict__ Vt,
    __hip_bfloat16* __restrict__ Ob) {
  const int lin = blockIdx.x;          // 0..2047
  const int xcd = lin & 7;
  const int idx = lin >> 3;            // 0..255
  const int h = xcd * 2 + (idx >> 7);  // 2 heads per XCD (K/V fits 4MiB L2)
  const int sub = idx & 127;
  const int tid = threadIdx.x;
  const int lane = tid & 63, w = tid >> 6;
  const int r = w ? (255 - sub) : sub; // 16-row q-tile index 0..255
  if (r >= 192) __builtin_amdgcn_s_setprio(1);  // long waves get issue priority
  const int nt = (r >> 2) + 1;
  const int q0 = r * 16;
  const int g = lane >> 4, c = lane & 15;
  const short8 qf = *reinterpret_cast<const short8*>(Qp + ((size_t)h * TT + q0 + c) * 32 + 8 * g);
  f32x4 o0 = {0.f, 0.f, 0.f, 0.f}, o1 = {0.f, 0.f, 0.f, 0.f};
  const f32x4 zz = {0.f, 0.f, 0.f, 0.f};
  float mst = -1e30f, lsum = 0.f;      // per-lane partial lsum (16 kv/lane/tile)

  const __hip_bfloat16* pkn = Kp + (size_t)h * TT * 32 + (size_t)c * 32 + 8 * g;
  const __hip_bfloat16* pv  = Vt + ((size_t)h * 32 + c) * TT + 4 * g;   // V^T row c
  const __hip_bfloat16* pv2 = pv + (size_t)16 * TT;                     // V^T row 16+c

  short8 kf[4];
#pragma unroll
  for (int ct = 0; ct < 4; ++ct)
    kf[ct] = *reinterpret_cast<const short8*>(pkn + ct * 512);
  pkn += 2048;

  for (int it = 0; it < nt; ++it) {
    // V loads for this tile (early issue); pi-permuted 8B granularity
    const short4v va0 = *reinterpret_cast<const short4v*>(pv);
    const short4v va1 = *reinterpret_cast<const short4v*>(pv + 16);
    const short4v va2 = *reinterpret_cast<const short4v*>(pv + 32);
    const short4v va3 = *reinterpret_cast<const short4v*>(pv + 48);
    const short4v vb0 = *reinterpret_cast<const short4v*>(pv2);
    const short4v vb1 = *reinterpret_cast<const short4v*>(pv2 + 16);
    const short4v vb2 = *reinterpret_cast<const short4v*>(pv2 + 32);
    const short4v vb3 = *reinterpret_cast<const short4v*>(pv2 + 48);
    pv += 64; pv2 += 64;
    // K prefetch for next tile
    short8 kn[4];
    if (it + 1 < nt) {
#pragma unroll
      for (int ct = 0; ct < 4; ++ct)
        kn[ct] = *reinterpret_cast<const short8*>(pkn + ct * 512);
      pkn += 2048;
    }
    f32x4 s[4];
#pragma unroll
    for (int ct = 0; ct < 4; ++ct)
      s[ct] = __builtin_amdgcn_mfma_f32_16x16x32_bf16(kf[ct], qf, zz, 0, 0, 0);  // swapped
    if (it == nt - 1) {  // diagonal tile: causal mask (k > q)
      const int kv0 = it * 64;
#pragma unroll
      for (int ct = 0; ct < 4; ++ct)
#pragma unroll
        for (int j = 0; j < 4; ++j)
          if (kv0 + ct * 16 + g * 4 + j > q0 + c) s[ct][j] = -1e30f;
    }
    // in-lane max over this lane's 16 scores
    float m01 = fmaxf(fmaxf(s[0][0], s[0][1]), fmaxf(s[0][2], s[0][3]));
    float m23 = fmaxf(fmaxf(s[1][0], s[1][1]), fmaxf(s[1][2], s[1][3]));
    float m45 = fmaxf(fmaxf(s[2][0], s[2][1]), fmaxf(s[2][2], s[2][3]));
    float m67 = fmaxf(fmaxf(s[3][0], s[3][1]), fmaxf(s[3][2], s[3][3]));
    float pm_ = fmaxf(fmaxf(m01, m23), fmaxf(m45, m67));
    if (__any(pm_ > mst + 8.0f)) {     // rare once m stabilizes (defer-max)
      float pm2 = fmaxf(pm_, __shfl_xor(pm_, 16, 64));
      pm2 = fmaxf(pm2, __shfl_xor(pm2, 32, 64));
      const float nm = fmaxf(mst, pm2);
      const float alpha = exp2f(mst - nm);
      mst = nm;
      lsum *= alpha;
#pragma unroll
      for (int j = 0; j < 4; ++j) { o0[j] *= alpha; o1[j] *= alpha; }
    }
    float ts = 0.f;
#pragma unroll
    for (int ct = 0; ct < 4; ++ct) {
#pragma unroll
      for (int j = 0; j < 4; ++j) s[ct][j] = exp2f(s[ct][j] - mst);
      ts += (s[ct][0] + s[ct][1]) + (s[ct][2] + s[ct][3]);
    }
    lsum += ts;
    // pack P to bf16 IN-LANE (pi permutation makes B-frag = own values)
    union { unsigned u[4]; short8 v8; } pb0, pb1;
    pb0.u[0] = pk2(s[0][0], s[0][1]);
    pb0.u[1] = pk2(s[0][2], s[0][3]);
    pb0.u[2] = pk2(s[1][0], s[1][1]);
    pb0.u[3] = pk2(s[1][2], s[1][3]);
    pb1.u[0] = pk2(s[2][0], s[2][1]);
    pb1.u[1] = pk2(s[2][2], s[2][3]);
    pb1.u[2] = pk2(s[3][0], s[3][1]);
    pb1.u[3] = pk2(s[3][2], s[3][3]);
    // A-frags: V^T with the same pi permutation
    const short8 aA0 = {va0[0], va0[1], va0[2], va0[3], va1[0], va1[1], va1[2], va1[3]};
    const short8 aA1 = {va2[0], va2[1], va2[2], va2[3], va3[0], va3[1], va3[2], va3[3]};
    const short8 aB0 = {vb0[0], vb0[1], vb0[2], vb0[3], vb1[0], vb1[1], vb1[2], vb1[3]};
    const short8 aB1 = {vb2[0], vb2[1], vb2[2], vb2[3], vb3[0], vb3[1], vb3[2], vb3[3]};
    // O^T accumulate: C col = q-row = lane c
    o0 = __builtin_amdgcn_mfma_f32_16x16x32_bf16(aA0, pb0.v8, o0, 0, 0, 0);
    o0 = __builtin_amdgcn_mfma_f32_16x16x32_bf16(aA1, pb1.v8, o0, 0, 0, 0);
    o1 = __builtin_amdgcn_mfma_f32_16x16x32_bf16(aB0, pb0.v8, o1, 0, 0, 0);
    o1 = __builtin_amdgcn_mfma_f32_16x16x32_bf16(aB1, pb1.v8, o1, 0, 0, 0);
#pragma unroll
    for (int ct = 0; ct < 4; ++ct) kf[ct] = kn[ct];
  }
  // single final lsum reduce across the 4 g-lanes of row c
  lsum += __shfl_xor(lsum, 16, 64);
  lsum += __shfl_xor(lsum, 32, 64);
  const float inv = 1.0f / lsum;
  const int row = q0 + c;
  __hip_bfloat16* dst = Ob + (size_t)row * DATTN + h * 32;
  short4v w0, w1;
#pragma unroll
  for (int j = 0; j < 4; ++j) { w0[j] = f2bf(o0[j] * inv); w1[j] = f2bf(o1[j] * inv); }
  *reinterpret_cast<short4v*>(dst + g * 4) = w0;
  *reinterpret_cast<short4v*>(dst + 16 + g * 4) = w1;
}

extern "C" void kernel_launch(void* const* d_in, const int* in_sizes, int n_in,
                              void* d_out, int out_size, void* d_ws, size_t ws_size,
                              hipStream_t stream) {
  const float* x   = (const float*)d_in[0];
  const float* qsw = (const float*)d_in[1];
  const float* ksw = (const float*)d_in[2];
  const float* qgw = (const float*)d_in[3];
  const float* kgw = (const float*)d_in[4];
  const float* vw  = (const float*)d_in[5];
  const float* ow  = (const float*)d_in[6];
  const float* ls  = (const float*)d_in[7];
  const int* posp  = (const int*)d_in[9];

  size_t off = 0;
  auto alloc = [&](size_t bytes) {
    char* p = (char*)d_ws + off;
    off += (bytes + 255) & ~(size_t)255;
    return (void*)p;
  };
  __hip_bfloat16* Xbf  = (__hip_bfloat16*)alloc((size_t)TT * DM * 2);
  __hip_bfloat16* Wcat = (__hip_bfloat16*)alloc((size_t)NPROJ * DM * 2);
  __hip_bfloat16* OW   = (__hip_bfloat16*)alloc((size_t)DM * DATTN * 2);
  __hip_bfloat16* proj = (__hip_bfloat16*)alloc((size_t)TT * NPROJ * 2);
  __hip_bfloat16* Qp   = (__hip_bfloat16*)alloc((size_t)NH * TT * 32 * 2);
  __hip_bfloat16* Kpk  = (__hip_bfloat16*)alloc((size_t)NH * TT * 32 * 2);
  __hip_bfloat16* Vt   = (__hip_bfloat16*)alloc((size_t)NH * 32 * TT * 2);
  __hip_bfloat16* Ob   = (__hip_bfloat16*)alloc((size_t)TT * DATTN * 2);

  k_f32_to_bf16<<<dim3((TT * DM / 4) / 256), 256, 0, stream>>>(x, Xbf, TT * DM / 4);
  k_f32_to_bf16<<<dim3((DM * DATTN / 4) / 256), 256, 0, stream>>>(ow, OW, DM * DATTN / 4);
  k_pack_wcat<<<dim3((NPROJ * DM / 4) / 256), 256, 0, stream>>>(qsw, ksw, qgw, kgw, vw, Wcat,
                                                                NPROJ * DM / 4);
  k_gemm_bt<1><<<dim3(TT / 128, NPROJ / 128), 256, 0, stream>>>(Xbf, Wcat, (void*)proj,
                                                                TT, NPROJ, DM);
  k_rope_pack<<<dim3(TT * NH / 256), 256, 0, stream>>>(proj, ls, posp, Qp, Kpk, Vt);
  k_attn<<<dim3(2048), 128, 0, stream>>>(Qp, Kpk, Vt, Ob);
  k_gemm_bt<0><<<dim3(TT / 128, DM / 128), 256, 0, stream>>>(Ob, OW, (void*)d_out,
                                                             TT, DM, DATTN);
}

// Round 9
// 143.196 us; speedup vs baseline: 1.4702x; 1.4702x over previous
//
#include <hip/hip_runtime.h>
#include <hip/hip_bf16.h>

typedef __attribute__((ext_vector_type(8))) short short8;
typedef __attribute__((ext_vector_type(4))) short short4v;
typedef __attribute__((ext_vector_type(4))) float f32x4;

#define TT 4096
#define DM 1024
#define NH 16
#define NPROJ 1280   // 128 qs + 128 ks + 256 qg + 256 kg + 512 v
#define DATTN 512

static __device__ __forceinline__ short f2bf(float f) {
  __hip_bfloat16 h = __float2bfloat16(f);
  return *reinterpret_cast<short*>(&h);
}
static __device__ __forceinline__ float bf2f(__hip_bfloat16 h) { return __bfloat162float(h); }

// ---------------- fp32 -> bf16 convert (x, out_w) ----------------
__global__ __launch_bounds__(256) void k_f32_to_bf16(const float* __restrict__ in,
                                                     __hip_bfloat16* __restrict__ out, int n4) {
  int i = blockIdx.x * blockDim.x + threadIdx.x;
  if (i >= n4) return;
  float4 v = reinterpret_cast<const float4*>(in)[i];
  short4v o;
  o[0] = f2bf(v.x); o[1] = f2bf(v.y); o[2] = f2bf(v.z); o[3] = f2bf(v.w);
  reinterpret_cast<short4v*>(out)[i] = o;
}

// ---------------- concat 5 weight matrices into (1280,1024) bf16 ----------------
__global__ __launch_bounds__(256) void k_pack_wcat(const float* __restrict__ qs,
    const float* __restrict__ ks, const float* __restrict__ qg, const float* __restrict__ kg,
    const float* __restrict__ vw, __hip_bfloat16* __restrict__ w, int n4) {
  int i = blockIdx.x * blockDim.x + threadIdx.x;
  if (i >= n4) return;
  int idx = i * 4;
  int row = idx >> 10;
  int col = idx & 1023;
  const float* src;
  if (row < 128)      src = qs + (size_t)row * DM;
  else if (row < 256) src = ks + (size_t)(row - 128) * DM;
  else if (row < 512) src = qg + (size_t)(row - 256) * DM;
  else if (row < 768) src = kg + (size_t)(row - 512) * DM;
  else                src = vw + (size_t)(row - 768) * DM;
  float4 v = *reinterpret_cast<const float4*>(src + col);
  short4v o;
  o[0] = f2bf(v.x); o[1] = f2bf(v.y); o[2] = f2bf(v.z); o[3] = f2bf(v.w);
  *reinterpret_cast<short4v*>(w + idx) = o;
}

// ---------------- bf16 GEMM, B^T layout: C[m][n] = sum_k A[m][k]*B[n][k] ----------------
template<int OUT_BF16>
__global__ __launch_bounds__(256) void k_gemm_bt(const __hip_bfloat16* __restrict__ A,
    const __hip_bfloat16* __restrict__ B, void* __restrict__ Cv, int M, int N, int K) {
  __shared__ alignas(16) __hip_bfloat16 lA[128 * 32];
  __shared__ alignas(16) __hip_bfloat16 lB[128 * 32];
  const int tid = threadIdx.x;
  const int lane = tid & 63;
  const int wid = tid >> 6;
  const int m0 = blockIdx.x * 128, n0 = blockIdx.y * 128;
  const int wm = (wid >> 1) * 64, wn = (wid & 1) * 64;
  const int srow = tid >> 2;          // 0..63
  const int scol = (tid & 3) * 8;     // bf16 elements
  const int fr = lane & 15, fk = (lane >> 4) * 8;
  f32x4 acc[4][4];
  const f32x4 zz = {0.f, 0.f, 0.f, 0.f};
#pragma unroll
  for (int m = 0; m < 4; ++m)
#pragma unroll
    for (int n = 0; n < 4; ++n) acc[m][n] = zz;

  for (int kt = 0; kt < K; kt += 32) {
    __syncthreads();
    {
      const __hip_bfloat16* ga0 = A + (size_t)(m0 + srow) * K + kt + scol;
      const __hip_bfloat16* ga1 = A + (size_t)(m0 + 64 + srow) * K + kt + scol;
      const __hip_bfloat16* gb0 = B + (size_t)(n0 + srow) * K + kt + scol;
      const __hip_bfloat16* gb1 = B + (size_t)(n0 + 64 + srow) * K + kt + scol;
      __builtin_amdgcn_global_load_lds((const __attribute__((address_space(1))) void*)ga0,
          (__attribute__((address_space(3))) void*)(lA + srow * 32 + scol), 16, 0, 0);
      __builtin_amdgcn_global_load_lds((const __attribute__((address_space(1))) void*)ga1,
          (__attribute__((address_space(3))) void*)(lA + (64 + srow) * 32 + scol), 16, 0, 0);
      __builtin_amdgcn_global_load_lds((const __attribute__((address_space(1))) void*)gb0,
          (__attribute__((address_space(3))) void*)(lB + srow * 32 + scol), 16, 0, 0);
      __builtin_amdgcn_global_load_lds((const __attribute__((address_space(1))) void*)gb1,
          (__attribute__((address_space(3))) void*)(lB + (64 + srow) * 32 + scol), 16, 0, 0);
    }
    __syncthreads();
    short8 af[4], bfr[4];
#pragma unroll
    for (int m = 0; m < 4; ++m)
      af[m] = *reinterpret_cast<const short8*>(lA + (wm + m * 16 + fr) * 32 + fk);
#pragma unroll
    for (int n = 0; n < 4; ++n)
      bfr[n] = *reinterpret_cast<const short8*>(lB + (wn + n * 16 + fr) * 32 + fk);
#pragma unroll
    for (int m = 0; m < 4; ++m)
#pragma unroll
      for (int n = 0; n < 4; ++n)
        acc[m][n] = __builtin_amdgcn_mfma_f32_16x16x32_bf16(af[m], bfr[n], acc[m][n], 0, 0, 0);
  }
  const int cr = (lane >> 4) * 4, cc = lane & 15;
#pragma unroll
  for (int m = 0; m < 4; ++m)
#pragma unroll
    for (int n = 0; n < 4; ++n)
#pragma unroll
      for (int j = 0; j < 4; ++j) {
        const int row = m0 + wm + m * 16 + cr + j;
        const int col = n0 + wn + n * 16 + cc;
        if (OUT_BF16)
          ((__hip_bfloat16*)Cv)[(size_t)row * N + col] = __float2bfloat16(acc[m][n][j]);
        else
          ((float*)Cv)[(size_t)row * N + col] = acc[m][n][j];
      }
}

// ---------------- RoPE + pack Q/K (H,T,32) and V^T (H,32,T) ----------------
// qscale folds 1/sqrt(24) * exp(logit_scale) * log2(e)  (softmax uses exp2)
__global__ __launch_bounds__(256) void k_rope_pack(const __hip_bfloat16* __restrict__ proj,
    const float* __restrict__ ls, const int* __restrict__ posp,
    __hip_bfloat16* __restrict__ Qp, __hip_bfloat16* __restrict__ Kp,
    __hip_bfloat16* __restrict__ Vt) {
  const int gid = blockIdx.x * blockDim.x + threadIdx.x;  // T*NH, t fastest
  const int t = gid & (TT - 1);
  const int h = gid >> 12;
  const __hip_bfloat16* pr = proj + (size_t)t * NPROJ;
  const float qscale = 0.20412414523193154f * 1.4426950408889634f * __expf(ls[h]);
  const float pos = (float)(t + posp[0]);
  const float invf[8] = {1.0f, 0.31622776601683794f, 0.1f, 0.031622776601683794f,
                         0.01f, 0.0031622776601683794f, 0.001f, 0.00031622776601683794f};
  short8 qv[4], kv[4];
  const short8 z8 = {0, 0, 0, 0, 0, 0, 0, 0};
  qv[3] = z8; kv[3] = z8;
#pragma unroll
  for (int i = 0; i < 8; ++i) {
    qv[0][i] = f2bf(bf2f(pr[h * 8 + i]) * qscale);
    kv[0][i] = f2bf(bf2f(pr[128 + h * 8 + i]));
  }
#pragma unroll
  for (int i = 0; i < 8; ++i) {
    const float ang = pos * invf[i];
    float ss, cc;
    __sincosf(ang, &ss, &cc);
    const float x1q = bf2f(pr[256 + h * 16 + i]), x2q = bf2f(pr[256 + h * 16 + 8 + i]);
    const float x1k = bf2f(pr[512 + h * 16 + i]), x2k = bf2f(pr[512 + h * 16 + 8 + i]);
    qv[1][i] = f2bf((x1q * cc - x2q * ss) * qscale);
    qv[2][i] = f2bf((x1q * ss + x2q * cc) * qscale);
    kv[1][i] = f2bf(x1k * cc - x2k * ss);
    kv[2][i] = f2bf(x1k * ss + x2k * cc);
  }
  short8* qdst = reinterpret_cast<short8*>(Qp + ((size_t)h * TT + t) * 32);
  short8* kdst = reinterpret_cast<short8*>(Kp + ((size_t)h * TT + t) * 32);
#pragma unroll
  for (int p = 0; p < 4; ++p) { qdst[p] = qv[p]; kdst[p] = kv[p]; }
#pragma unroll
  for (int i = 0; i < 32; ++i)
    Vt[((size_t)h * 32 + i) * TT + t] = pr[768 + h * 32 + i];
}

// ---------------- causal flash attention, LDS-shared K/V (4-wave blocks) ----------------
// 512 blocks x 4 waves. Block = (head, q-block pair {63-p, p}): each segment covers
// 64 q-rows (wave w: rows +16w..+16w+15); K(64x32) & V^T(32x64) tiles staged to LDS
// once per block per tile (2 global_load_lds), double-buffered, 1 barrier/tile.
// => per-tile VMEM / q-row is 4x smaller than per-wave streaming.
// Segments (64-p-1+1)+(p+1) = 65 tiles: all blocks uniform -> no tail.
// Per-wave math identical to R5 (swapped QK, defer-max, O^T epilogue).
__global__ __launch_bounds__(256) void k_attn(const __hip_bfloat16* __restrict__ Qp,
    const __hip_bfloat16* __restrict__ Kp, const __hip_bfloat16* __restrict__ Vt,
    __hip_bfloat16* __restrict__ Ob) {
  __shared__ alignas(16) __hip_bfloat16 lK[2][64 * 32];   // 4KB each
  __shared__ alignas(16) __hip_bfloat16 lV[2][32 * 64];   // 4KB each (swizzled cols)
  __shared__ alignas(16) __hip_bfloat16 Plds[4][16][72];
  const int lin = blockIdx.x;           // 0..511
  const int xcd = lin & 7;
  const int idx = lin >> 3;             // 0..63
  const int h = xcd * 2 + (idx >> 5);   // 2 heads per XCD
  const int pi_ = idx & 31;             // pair index
  const int tid = threadIdx.x;
  const int lane = tid & 63, w = tid >> 6;
  const int g = lane >> 4, c = lane & 15;
  // staging lane mapping
  const int srK = tid >> 2, scK = (tid & 3) * 8;                       // K row, col
  const int srV = tid >> 3, scV = ((tid & 7) ^ (((tid >> 3) & 1) << 2)) * 8;  // V row, swz col
  const __hip_bfloat16* Kh = Kp + (size_t)h * TT * 32;
  const __hip_bfloat16* Vh = Vt + (size_t)h * 32 * TT;
  const f32x4 zz = {0.f, 0.f, 0.f, 0.f};
  const int sw = (c & 1) << 6;          // V read swizzle (byte)

#pragma unroll 1
  for (int seg = 0; seg < 2; ++seg) {
    const int qb = seg == 0 ? (63 - pi_) : pi_;
    const int nt = qb + 1;
    const int q0 = qb * 64;
    const int qrow = q0 + w * 16 + c;
    const short8 qf =
        *reinterpret_cast<const short8*>(Qp + ((size_t)h * TT + qrow) * 32 + 8 * g);
    f32x4 o0 = zz, o1 = zz;
    float mst = -1e30f, lsum = 0.f;
    int cur = 0;
    // prologue: stage tile 0 into buf 0
    __builtin_amdgcn_global_load_lds(
        (const __attribute__((address_space(1))) void*)(Kh + (size_t)srK * 32 + scK),
        (__attribute__((address_space(3))) void*)(lK[0] + tid * 8), 16, 0, 0);
    __builtin_amdgcn_global_load_lds(
        (const __attribute__((address_space(1))) void*)(Vh + (size_t)srV * TT + scV),
        (__attribute__((address_space(3))) void*)(lV[0] + tid * 8), 16, 0, 0);

    for (int it = 0; it < nt; ++it) {
      __syncthreads();  // buf[cur] staged (vmcnt drain) + all waves done with buf[cur^1]
      if (it + 1 < nt) {
        const int kv1 = (it + 1) * 64;
        __builtin_amdgcn_global_load_lds(
            (const __attribute__((address_space(1))) void*)(Kh + (size_t)(kv1 + srK) * 32 + scK),
            (__attribute__((address_space(3))) void*)(lK[cur ^ 1] + tid * 8), 16, 0, 0);
        __builtin_amdgcn_global_load_lds(
            (const __attribute__((address_space(1))) void*)(Vh + (size_t)srV * TT + kv1 + scV),
            (__attribute__((address_space(3))) void*)(lV[cur ^ 1] + tid * 8), 16, 0, 0);
      }
      // K fragments from LDS (bank-even: group = g + 4*(c&1))
      const char* kb = (const char*)lK[cur];
      short8 kf[4];
#pragma unroll
      for (int ct = 0; ct < 4; ++ct)
        kf[ct] = *reinterpret_cast<const short8*>(kb + (ct * 16 + c) * 64 + 16 * g);
      // V fragments (swizzled layout)
      const char* vb = (const char*)lV[cur];
      const short8 v00 = *reinterpret_cast<const short8*>(vb + c * 128 + ((16 * g) ^ sw));
      const short8 v01 = *reinterpret_cast<const short8*>(vb + c * 128 + ((64 + 16 * g) ^ sw));
      const short8 v10 = *reinterpret_cast<const short8*>(vb + (16 + c) * 128 + ((16 * g) ^ sw));
      const short8 v11 = *reinterpret_cast<const short8*>(vb + (16 + c) * 128 + ((64 + 16 * g) ^ sw));
      f32x4 s[4];
#pragma unroll
      for (int ct = 0; ct < 4; ++ct)
        s[ct] = __builtin_amdgcn_mfma_f32_16x16x32_bf16(kf[ct], qf, zz, 0, 0, 0);  // swapped
      if (it == nt - 1) {  // diagonal tile: kv0 == q0; mask k > q
#pragma unroll
        for (int ct = 0; ct < 4; ++ct)
#pragma unroll
          for (int j = 0; j < 4; ++j)
            if (ct * 16 + g * 4 + j > w * 16 + c) s[ct][j] = -1e30f;
      }
      // in-lane max over 16 scores
      float m01 = fmaxf(fmaxf(s[0][0], s[0][1]), fmaxf(s[0][2], s[0][3]));
      float m23 = fmaxf(fmaxf(s[1][0], s[1][1]), fmaxf(s[1][2], s[1][3]));
      float m45 = fmaxf(fmaxf(s[2][0], s[2][1]), fmaxf(s[2][2], s[2][3]));
      float m67 = fmaxf(fmaxf(s[3][0], s[3][1]), fmaxf(s[3][2], s[3][3]));
      float pm_ = fmaxf(fmaxf(m01, m23), fmaxf(m45, m67));
      if (__any(pm_ > mst + 8.0f)) {  // defer-max: rare once m stabilizes
        float pm2 = fmaxf(pm_, __shfl_xor(pm_, 16, 64));
        pm2 = fmaxf(pm2, __shfl_xor(pm2, 32, 64));
        const float nm = fmaxf(mst, pm2);
        const float alpha = exp2f(mst - nm);
        mst = nm;
        lsum *= alpha;
#pragma unroll
        for (int j = 0; j < 4; ++j) { o0[j] *= alpha; o1[j] *= alpha; }
      }
      float ts = 0.f;
#pragma unroll
      for (int ct = 0; ct < 4; ++ct) {
#pragma unroll
        for (int j = 0; j < 4; ++j) s[ct][j] = exp2f(s[ct][j] - mst);
        ts += (s[ct][0] + s[ct][1]) + (s[ct][2] + s[ct][3]);
      }
      lsum += ts;
      // P -> LDS (packed bf16 pairs), per-wave private slice
#pragma unroll
      for (int ct = 0; ct < 4; ++ct) {
        float2 p01; p01.x = s[ct][0]; p01.y = s[ct][1];
        float2 p23; p23.x = s[ct][2]; p23.y = s[ct][3];
        __hip_bfloat162 b01 = __float22bfloat162_rn(p01);
        __hip_bfloat162 b23 = __float22bfloat162_rn(p23);
        *reinterpret_cast<__hip_bfloat162*>(&Plds[w][c][ct * 16 + g * 4]) = b01;
        *reinterpret_cast<__hip_bfloat162*>(&Plds[w][c][ct * 16 + g * 4 + 2]) = b23;
      }
      const short8 pf0 = *reinterpret_cast<const short8*>(&Plds[w][c][8 * g]);
      const short8 pf1 = *reinterpret_cast<const short8*>(&Plds[w][c][32 + 8 * g]);
      // O^T: C col = q-row = lane c
      o0 = __builtin_amdgcn_mfma_f32_16x16x32_bf16(v00, pf0, o0, 0, 0, 0);
      o0 = __builtin_amdgcn_mfma_f32_16x16x32_bf16(v01, pf1, o0, 0, 0, 0);
      o1 = __builtin_amdgcn_mfma_f32_16x16x32_bf16(v10, pf0, o1, 0, 0, 0);
      o1 = __builtin_amdgcn_mfma_f32_16x16x32_bf16(v11, pf1, o1, 0, 0, 0);
      cur ^= 1;
    }
    // final lsum reduce across g-lanes of row c; write Ob
    lsum += __shfl_xor(lsum, 16, 64);
    lsum += __shfl_xor(lsum, 32, 64);
    const float inv = 1.0f / lsum;
    __hip_bfloat16* dst = Ob + (size_t)qrow * DATTN + h * 32;
    short4v w0, w1;
#pragma unroll
    for (int j = 0; j < 4; ++j) { w0[j] = f2bf(o0[j] * inv); w1[j] = f2bf(o1[j] * inv); }
    *reinterpret_cast<short4v*>(dst + g * 4) = w0;
    *reinterpret_cast<short4v*>(dst + 16 + g * 4) = w1;
    __syncthreads();  // protect LDS before next segment's prologue staging
  }
}

extern "C" void kernel_launch(void* const* d_in, const int* in_sizes, int n_in,
                              void* d_out, int out_size, void* d_ws, size_t ws_size,
                              hipStream_t stream) {
  const float* x   = (const float*)d_in[0];
  const float* qsw = (const float*)d_in[1];
  const float* ksw = (const float*)d_in[2];
  const float* qgw = (const float*)d_in[3];
  const float* kgw = (const float*)d_in[4];
  const float* vw  = (const float*)d_in[5];
  const float* ow  = (const float*)d_in[6];
  const float* ls  = (const float*)d_in[7];
  const int* posp  = (const int*)d_in[9];

  size_t off = 0;
  auto alloc = [&](size_t bytes) {
    char* p = (char*)d_ws + off;
    off += (bytes + 255) & ~(size_t)255;
    return (void*)p;
  };
  __hip_bfloat16* Xbf  = (__hip_bfloat16*)alloc((size_t)TT * DM * 2);
  __hip_bfloat16* Wcat = (__hip_bfloat16*)alloc((size_t)NPROJ * DM * 2);
  __hip_bfloat16* OW   = (__hip_bfloat16*)alloc((size_t)DM * DATTN * 2);
  __hip_bfloat16* proj = (__hip_bfloat16*)alloc((size_t)TT * NPROJ * 2);
  __hip_bfloat16* Qp   = (__hip_bfloat16*)alloc((size_t)NH * TT * 32 * 2);
  __hip_bfloat16* Kpk  = (__hip_bfloat16*)alloc((size_t)NH * TT * 32 * 2);
  __hip_bfloat16* Vt   = (__hip_bfloat16*)alloc((size_t)NH * 32 * TT * 2);
  __hip_bfloat16* Ob   = (__hip_bfloat16*)alloc((size_t)TT * DATTN * 2);

  k_f32_to_bf16<<<dim3((TT * DM / 4) / 256), 256, 0, stream>>>(x, Xbf, TT * DM / 4);
  k_f32_to_bf16<<<dim3((DM * DATTN / 4) / 256), 256, 0, stream>>>(ow, OW, DM * DATTN / 4);
  k_pack_wcat<<<dim3((NPROJ * DM / 4) / 256), 256, 0, stream>>>(qsw, ksw, qgw, kgw, vw, Wcat,
                                                                NPROJ * DM / 4);
  k_gemm_bt<1><<<dim3(TT / 128, NPROJ / 128), 256, 0, stream>>>(Xbf, Wcat, (void*)proj,
                                                                TT, NPROJ, DM);
  k_rope_pack<<<dim3(TT * NH / 256), 256, 0, stream>>>(proj, ls, posp, Qp, Kpk, Vt);
  k_attn<<<dim3(512), 256, 0, stream>>>(Qp, Kpk, Vt, Ob);
  k_gemm_bt<0><<<dim3(TT / 128, DM / 128), 256, 0, stream>>>(Ob, OW, (void*)d_out,
                                                             TT, DM, DATTN);
}

// Round 10
// 138.373 us; speedup vs baseline: 1.5214x; 1.0349x over previous
//
#include <hip/hip_runtime.h>
#include <hip/hip_bf16.h>

typedef __attribute__((ext_vector_type(8))) short short8;
typedef __attribute__((ext_vector_type(4))) short short4v;
typedef __attribute__((ext_vector_type(4))) float f32x4;

#define TT 4096
#define DM 1024
#define NH 16
#define NPROJ 1280   // 128 qs + 128 ks + 256 qg + 256 kg + 512 v
#define DATTN 512

static __device__ __forceinline__ short f2bf(float f) {
  __hip_bfloat16 h = __float2bfloat16(f);
  return *reinterpret_cast<short*>(&h);
}
static __device__ __forceinline__ float bf2f(__hip_bfloat16 h) { return __bfloat162float(h); }

// ---------------- fp32 -> bf16 convert (x, out_w) ----------------
__global__ __launch_bounds__(256) void k_f32_to_bf16(const float* __restrict__ in,
                                                     __hip_bfloat16* __restrict__ out, int n4) {
  int i = blockIdx.x * blockDim.x + threadIdx.x;
  if (i >= n4) return;
  float4 v = reinterpret_cast<const float4*>(in)[i];
  short4v o;
  o[0] = f2bf(v.x); o[1] = f2bf(v.y); o[2] = f2bf(v.z); o[3] = f2bf(v.w);
  reinterpret_cast<short4v*>(out)[i] = o;
}

// ---------------- concat 5 weight matrices into (1280,1024) bf16 ----------------
__global__ __launch_bounds__(256) void k_pack_wcat(const float* __restrict__ qs,
    const float* __restrict__ ks, const float* __restrict__ qg, const float* __restrict__ kg,
    const float* __restrict__ vw, __hip_bfloat16* __restrict__ w, int n4) {
  int i = blockIdx.x * blockDim.x + threadIdx.x;
  if (i >= n4) return;
  int idx = i * 4;
  int row = idx >> 10;
  int col = idx & 1023;
  const float* src;
  if (row < 128)      src = qs + (size_t)row * DM;
  else if (row < 256) src = ks + (size_t)(row - 128) * DM;
  else if (row < 512) src = qg + (size_t)(row - 256) * DM;
  else if (row < 768) src = kg + (size_t)(row - 512) * DM;
  else                src = vw + (size_t)(row - 768) * DM;
  float4 v = *reinterpret_cast<const float4*>(src + col);
  short4v o;
  o[0] = f2bf(v.x); o[1] = f2bf(v.y); o[2] = f2bf(v.z); o[3] = f2bf(v.w);
  *reinterpret_cast<short4v*>(w + idx) = o;
}

// ---------------- bf16 GEMM, B^T layout: C[m][n] = sum_k A[m][k]*B[n][k] ----------------
template<int OUT_BF16>
__global__ __launch_bounds__(256) void k_gemm_bt(const __hip_bfloat16* __restrict__ A,
    const __hip_bfloat16* __restrict__ B, void* __restrict__ Cv, int M, int N, int K) {
  __shared__ alignas(16) __hip_bfloat16 lA[128 * 32];
  __shared__ alignas(16) __hip_bfloat16 lB[128 * 32];
  const int tid = threadIdx.x;
  const int lane = tid & 63;
  const int wid = tid >> 6;
  const int m0 = blockIdx.x * 128, n0 = blockIdx.y * 128;
  const int wm = (wid >> 1) * 64, wn = (wid & 1) * 64;
  const int srow = tid >> 2;          // 0..63
  const int scol = (tid & 3) * 8;     // bf16 elements
  const int fr = lane & 15, fk = (lane >> 4) * 8;
  f32x4 acc[4][4];
  const f32x4 zz = {0.f, 0.f, 0.f, 0.f};
#pragma unroll
  for (int m = 0; m < 4; ++m)
#pragma unroll
    for (int n = 0; n < 4; ++n) acc[m][n] = zz;

  for (int kt = 0; kt < K; kt += 32) {
    __syncthreads();
    {
      const __hip_bfloat16* ga0 = A + (size_t)(m0 + srow) * K + kt + scol;
      const __hip_bfloat16* ga1 = A + (size_t)(m0 + 64 + srow) * K + kt + scol;
      const __hip_bfloat16* gb0 = B + (size_t)(n0 + srow) * K + kt + scol;
      const __hip_bfloat16* gb1 = B + (size_t)(n0 + 64 + srow) * K + kt + scol;
      __builtin_amdgcn_global_load_lds((const __attribute__((address_space(1))) void*)ga0,
          (__attribute__((address_space(3))) void*)(lA + srow * 32 + scol), 16, 0, 0);
      __builtin_amdgcn_global_load_lds((const __attribute__((address_space(1))) void*)ga1,
          (__attribute__((address_space(3))) void*)(lA + (64 + srow) * 32 + scol), 16, 0, 0);
      __builtin_amdgcn_global_load_lds((const __attribute__((address_space(1))) void*)gb0,
          (__attribute__((address_space(3))) void*)(lB + srow * 32 + scol), 16, 0, 0);
      __builtin_amdgcn_global_load_lds((const __attribute__((address_space(1))) void*)gb1,
          (__attribute__((address_space(3))) void*)(lB + (64 + srow) * 32 + scol), 16, 0, 0);
    }
    __syncthreads();
    short8 af[4], bfr[4];
#pragma unroll
    for (int m = 0; m < 4; ++m)
      af[m] = *reinterpret_cast<const short8*>(lA + (wm + m * 16 + fr) * 32 + fk);
#pragma unroll
    for (int n = 0; n < 4; ++n)
      bfr[n] = *reinterpret_cast<const short8*>(lB + (wn + n * 16 + fr) * 32 + fk);
#pragma unroll
    for (int m = 0; m < 4; ++m)
#pragma unroll
      for (int n = 0; n < 4; ++n)
        acc[m][n] = __builtin_amdgcn_mfma_f32_16x16x32_bf16(af[m], bfr[n], acc[m][n], 0, 0, 0);
  }
  const int cr = (lane >> 4) * 4, cc = lane & 15;
#pragma unroll
  for (int m = 0; m < 4; ++m)
#pragma unroll
    for (int n = 0; n < 4; ++n)
#pragma unroll
      for (int j = 0; j < 4; ++j) {
        const int row = m0 + wm + m * 16 + cr + j;
        const int col = n0 + wn + n * 16 + cc;
        if (OUT_BF16)
          ((__hip_bfloat16*)Cv)[(size_t)row * N + col] = __float2bfloat16(acc[m][n][j]);
        else
          ((float*)Cv)[(size_t)row * N + col] = acc[m][n][j];
      }
}

// ---------------- RoPE + pack Q/K (H,T,32) and V^T (H,32,T) ----------------
// qscale folds 1/sqrt(24) * exp(logit_scale) * log2(e)  (softmax uses exp2)
__global__ __launch_bounds__(256) void k_rope_pack(const __hip_bfloat16* __restrict__ proj,
    const float* __restrict__ ls, const int* __restrict__ posp,
    __hip_bfloat16* __restrict__ Qp, __hip_bfloat16* __restrict__ Kp,
    __hip_bfloat16* __restrict__ Vt) {
  const int gid = blockIdx.x * blockDim.x + threadIdx.x;  // T*NH, t fastest
  const int t = gid & (TT - 1);
  const int h = gid >> 12;
  const __hip_bfloat16* pr = proj + (size_t)t * NPROJ;
  const float qscale = 0.20412414523193154f * 1.4426950408889634f * __expf(ls[h]);
  const float pos = (float)(t + posp[0]);
  const float invf[8] = {1.0f, 0.31622776601683794f, 0.1f, 0.031622776601683794f,
                         0.01f, 0.0031622776601683794f, 0.001f, 0.00031622776601683794f};
  short8 qv[4], kv[4];
  const short8 z8 = {0, 0, 0, 0, 0, 0, 0, 0};
  qv[3] = z8; kv[3] = z8;
#pragma unroll
  for (int i = 0; i < 8; ++i) {
    qv[0][i] = f2bf(bf2f(pr[h * 8 + i]) * qscale);
    kv[0][i] = f2bf(bf2f(pr[128 + h * 8 + i]));
  }
#pragma unroll
  for (int i = 0; i < 8; ++i) {
    const float ang = pos * invf[i];
    float ss, cc;
    __sincosf(ang, &ss, &cc);
    const float x1q = bf2f(pr[256 + h * 16 + i]), x2q = bf2f(pr[256 + h * 16 + 8 + i]);
    const float x1k = bf2f(pr[512 + h * 16 + i]), x2k = bf2f(pr[512 + h * 16 + 8 + i]);
    qv[1][i] = f2bf((x1q * cc - x2q * ss) * qscale);
    qv[2][i] = f2bf((x1q * ss + x2q * cc) * qscale);
    kv[1][i] = f2bf(x1k * cc - x2k * ss);
    kv[2][i] = f2bf(x1k * ss + x2k * cc);
  }
  short8* qdst = reinterpret_cast<short8*>(Qp + ((size_t)h * TT + t) * 32);
  short8* kdst = reinterpret_cast<short8*>(Kp + ((size_t)h * TT + t) * 32);
#pragma unroll
  for (int p = 0; p < 4; ++p) { qdst[p] = qv[p]; kdst[p] = kv[p]; }
#pragma unroll
  for (int i = 0; i < 32; ++i)
    Vt[((size_t)h * 32 + i) * TT + t] = pr[768 + h * 32 + i];
}

// ---------------- causal flash attention, LDS-shared K/V, conflict-free layout ----------
// 512 blocks x 4 waves; block = (head, pair {63-p, p}); uniform 65 tiles/block.
// LDS layouts chosen = exact read order, so every ds_read is base + lane*16
// (conflict-free); staging inverse-permutes the GLOBAL source per lane (rule #21):
//   K:  LDS[ct][g][c] 16B  <- K[kv=ct*16+c][8g..8g+8)
//   V:  LDS[kvb][db][g][c] 16B <- V^T[d=db*16+c][kvb*32+8g..+8)
__global__ __launch_bounds__(256) void k_attn(const __hip_bfloat16* __restrict__ Qp,
    const __hip_bfloat16* __restrict__ Kp, const __hip_bfloat16* __restrict__ Vt,
    __hip_bfloat16* __restrict__ Ob) {
  __shared__ alignas(16) __hip_bfloat16 lK[2][64 * 32];   // 4KB each
  __shared__ alignas(16) __hip_bfloat16 lV[2][32 * 64];   // 4KB each
  __shared__ alignas(16) __hip_bfloat16 Plds[4][16][72];
  const int lin = blockIdx.x;           // 0..511
  const int xcd = lin & 7;
  const int idx = lin >> 3;             // 0..63
  const int h = xcd * 2 + (idx >> 5);   // 2 heads per XCD
  const int pi_ = idx & 31;             // pair index
  const int tid = threadIdx.x;
  const int lane = tid & 63, w = tid >> 6;
  const int g = lane >> 4, c = lane & 15;
  // staging source mapping (inverse of the LDS read permutation)
  const int krow = (tid >> 6) * 16 + (tid & 15);           // kv row within tile
  const int kcol = ((tid >> 4) & 3) * 8;                   // dim slot
  const int vrow = ((tid >> 6) & 1) * 16 + (tid & 15);     // d row
  const int vcol = ((tid >> 7) & 1) * 32 + ((tid >> 4) & 3) * 8;  // kv slot within tile
  const __hip_bfloat16* Kh = Kp + (size_t)h * TT * 32 + (size_t)krow * 32 + kcol;
  const __hip_bfloat16* Vh = Vt + (size_t)h * 32 * TT + (size_t)vrow * TT + vcol;
  const f32x4 zz = {0.f, 0.f, 0.f, 0.f};

#pragma unroll 1
  for (int seg = 0; seg < 2; ++seg) {
    const int qb = seg == 0 ? (63 - pi_) : pi_;
    const int nt = qb + 1;
    const int qrow = qb * 64 + w * 16 + c;
    const short8 qf =
        *reinterpret_cast<const short8*>(Qp + ((size_t)h * TT + qrow) * 32 + 8 * g);
    f32x4 o0 = zz, o1 = zz;
    float mst = -1e30f, lsum = 0.f;
    int cur = 0;
    // prologue: stage tile 0 into buf 0
    __builtin_amdgcn_global_load_lds(
        (const __attribute__((address_space(1))) void*)Kh,
        (__attribute__((address_space(3))) void*)(lK[0] + tid * 8), 16, 0, 0);
    __builtin_amdgcn_global_load_lds(
        (const __attribute__((address_space(1))) void*)Vh,
        (__attribute__((address_space(3))) void*)(lV[0] + tid * 8), 16, 0, 0);

    for (int it = 0; it < nt; ++it) {
      __syncthreads();  // buf[cur] staged + all waves done with buf[cur^1]
      if (it + 1 < nt) {
        const int kv1 = (it + 1) * 64;
        __builtin_amdgcn_global_load_lds(
            (const __attribute__((address_space(1))) void*)(Kh + (size_t)kv1 * 32),
            (__attribute__((address_space(3))) void*)(lK[cur ^ 1] + tid * 8), 16, 0, 0);
        __builtin_amdgcn_global_load_lds(
            (const __attribute__((address_space(1))) void*)(Vh + kv1),
            (__attribute__((address_space(3))) void*)(lV[cur ^ 1] + tid * 8), 16, 0, 0);
      }
      // K fragments: addr = base + lane*16 (conflict-free)
      const char* kb = (const char*)lK[cur];
      short8 kf[4];
#pragma unroll
      for (int ct = 0; ct < 4; ++ct)
        kf[ct] = *reinterpret_cast<const short8*>(kb + ct * 1024 + lane * 16);
      // V fragments: addr = base + lane*16 (conflict-free)
      const char* vb = (const char*)lV[cur];
      const short8 v00 = *reinterpret_cast<const short8*>(vb + lane * 16);
      const short8 v10 = *reinterpret_cast<const short8*>(vb + 1024 + lane * 16);
      const short8 v01 = *reinterpret_cast<const short8*>(vb + 2048 + lane * 16);
      const short8 v11 = *reinterpret_cast<const short8*>(vb + 3072 + lane * 16);
      f32x4 s[4];
#pragma unroll
      for (int ct = 0; ct < 4; ++ct)
        s[ct] = __builtin_amdgcn_mfma_f32_16x16x32_bf16(kf[ct], qf, zz, 0, 0, 0);  // swapped
      if (it == nt - 1) {  // diagonal tile: mask k > q
#pragma unroll
        for (int ct = 0; ct < 4; ++ct)
#pragma unroll
          for (int j = 0; j < 4; ++j)
            if (ct * 16 + g * 4 + j > w * 16 + c) s[ct][j] = -1e30f;
      }
      // in-lane max over 16 scores
      float m01 = fmaxf(fmaxf(s[0][0], s[0][1]), fmaxf(s[0][2], s[0][3]));
      float m23 = fmaxf(fmaxf(s[1][0], s[1][1]), fmaxf(s[1][2], s[1][3]));
      float m45 = fmaxf(fmaxf(s[2][0], s[2][1]), fmaxf(s[2][2], s[2][3]));
      float m67 = fmaxf(fmaxf(s[3][0], s[3][1]), fmaxf(s[3][2], s[3][3]));
      float pm_ = fmaxf(fmaxf(m01, m23), fmaxf(m45, m67));
      if (__any(pm_ > mst + 8.0f)) {  // defer-max
        float pm2 = fmaxf(pm_, __shfl_xor(pm_, 16, 64));
        pm2 = fmaxf(pm2, __shfl_xor(pm2, 32, 64));
        const float nm = fmaxf(mst, pm2);
        const float alpha = exp2f(mst - nm);
        mst = nm;
        lsum *= alpha;
#pragma unroll
        for (int j = 0; j < 4; ++j) { o0[j] *= alpha; o1[j] *= alpha; }
      }
      float ts = 0.f;
#pragma unroll
      for (int ct = 0; ct < 4; ++ct) {
#pragma unroll
        for (int j = 0; j < 4; ++j) s[ct][j] = exp2f(s[ct][j] - mst);
        ts += (s[ct][0] + s[ct][1]) + (s[ct][2] + s[ct][3]);
      }
      lsum += ts;
      // P -> LDS (packed bf16 pairs), per-wave private slice (2-way max: free)
#pragma unroll
      for (int ct = 0; ct < 4; ++ct) {
        float2 p01; p01.x = s[ct][0]; p01.y = s[ct][1];
        float2 p23; p23.x = s[ct][2]; p23.y = s[ct][3];
        __hip_bfloat162 b01 = __float22bfloat162_rn(p01);
        __hip_bfloat162 b23 = __float22bfloat162_rn(p23);
        *reinterpret_cast<__hip_bfloat162*>(&Plds[w][c][ct * 16 + g * 4]) = b01;
        *reinterpret_cast<__hip_bfloat162*>(&Plds[w][c][ct * 16 + g * 4 + 2]) = b23;
      }
      const short8 pf0 = *reinterpret_cast<const short8*>(&Plds[w][c][8 * g]);
      const short8 pf1 = *reinterpret_cast<const short8*>(&Plds[w][c][32 + 8 * g]);
      // O^T: C col = q-row = lane c
      o0 = __builtin_amdgcn_mfma_f32_16x16x32_bf16(v00, pf0, o0, 0, 0, 0);
      o0 = __builtin_amdgcn_mfma_f32_16x16x32_bf16(v01, pf1, o0, 0, 0, 0);
      o1 = __builtin_amdgcn_mfma_f32_16x16x32_bf16(v10, pf0, o1, 0, 0, 0);
      o1 = __builtin_amdgcn_mfma_f32_16x16x32_bf16(v11, pf1, o1, 0, 0, 0);
      cur ^= 1;
    }
    // final lsum reduce across g-lanes of row c; write Ob
    lsum += __shfl_xor(lsum, 16, 64);
    lsum += __shfl_xor(lsum, 32, 64);
    const float inv = 1.0f / lsum;
    __hip_bfloat16* dst = Ob + (size_t)qrow * DATTN + h * 32;
    short4v w0, w1;
#pragma unroll
    for (int j = 0; j < 4; ++j) { w0[j] = f2bf(o0[j] * inv); w1[j] = f2bf(o1[j] * inv); }
    *reinterpret_cast<short4v*>(dst + g * 4) = w0;
    *reinterpret_cast<short4v*>(dst + 16 + g * 4) = w1;
    __syncthreads();  // protect LDS before next segment's prologue staging
  }
}

extern "C" void kernel_launch(void* const* d_in, const int* in_sizes, int n_in,
                              void* d_out, int out_size, void* d_ws, size_t ws_size,
                              hipStream_t stream) {
  const float* x   = (const float*)d_in[0];
  const float* qsw = (const float*)d_in[1];
  const float* ksw = (const float*)d_in[2];
  const float* qgw = (const float*)d_in[3];
  const float* kgw = (const float*)d_in[4];
  const float* vw  = (const float*)d_in[5];
  const float* ow  = (const float*)d_in[6];
  const float* ls  = (const float*)d_in[7];
  const int* posp  = (const int*)d_in[9];

  size_t off = 0;
  auto alloc = [&](size_t bytes) {
    char* p = (char*)d_ws + off;
    off += (bytes + 255) & ~(size_t)255;
    return (void*)p;
  };
  __hip_bfloat16* Xbf  = (__hip_bfloat16*)alloc((size_t)TT * DM * 2);
  __hip_bfloat16* Wcat = (__hip_bfloat16*)alloc((size_t)NPROJ * DM * 2);
  __hip_bfloat16* OW   = (__hip_bfloat16*)alloc((size_t)DM * DATTN * 2);
  __hip_bfloat16* proj = (__hip_bfloat16*)alloc((size_t)TT * NPROJ * 2);
  __hip_bfloat16* Qp   = (__hip_bfloat16*)alloc((size_t)NH * TT * 32 * 2);
  __hip_bfloat16* Kpk  = (__hip_bfloat16*)alloc((size_t)NH * TT * 32 * 2);
  __hip_bfloat16* Vt   = (__hip_bfloat16*)alloc((size_t)NH * 32 * TT * 2);
  __hip_bfloat16* Ob   = (__hip_bfloat16*)alloc((size_t)TT * DATTN * 2);

  k_f32_to_bf16<<<dim3((TT * DM / 4) / 256), 256, 0, stream>>>(x, Xbf, TT * DM / 4);
  k_f32_to_bf16<<<dim3((DM * DATTN / 4) / 256), 256, 0, stream>>>(ow, OW, DM * DATTN / 4);
  k_pack_wcat<<<dim3((NPROJ * DM / 4) / 256), 256, 0, stream>>>(qsw, ksw, qgw, kgw, vw, Wcat,
                                                                NPROJ * DM / 4);
  k_gemm_bt<1><<<dim3(TT / 128, NPROJ / 128), 256, 0, stream>>>(Xbf, Wcat, (void*)proj,
                                                                TT, NPROJ, DM);
  k_rope_pack<<<dim3(TT * NH / 256), 256, 0, stream>>>(proj, ls, posp, Qp, Kpk, Vt);
  k_attn<<<dim3(512), 256, 0, stream>>>(Qp, Kpk, Vt, Ob);
  k_gemm_bt<0><<<dim3(TT / 128, DM / 128), 256, 0, stream>>>(Ob, OW, (void*)d_out,
                                                             TT, DM, DATTN);
}

// Round 11
// 131.757 us; speedup vs baseline: 1.5978x; 1.0502x over previous
//
#include <hip/hip_runtime.h>
#include <hip/hip_bf16.h>

typedef __attribute__((ext_vector_type(8))) short short8;
typedef __attribute__((ext_vector_type(4))) short short4v;
typedef __attribute__((ext_vector_type(4))) float f32x4;

#define TT 4096
#define DM 1024
#define NH 16
#define NPROJ 1280   // 128 qs + 128 ks + 256 qg + 256 kg + 512 v
#define DATTN 512

static __device__ __forceinline__ short f2bf(float f) {
  __hip_bfloat16 h = __float2bfloat16(f);
  return *reinterpret_cast<short*>(&h);
}
static __device__ __forceinline__ float bf2f(__hip_bfloat16 h) { return __bfloat162float(h); }

// ---------------- fp32 -> bf16 convert (x, out_w) ----------------
__global__ __launch_bounds__(256) void k_f32_to_bf16(const float* __restrict__ in,
                                                     __hip_bfloat16* __restrict__ out, int n4) {
  int i = blockIdx.x * blockDim.x + threadIdx.x;
  if (i >= n4) return;
  float4 v = reinterpret_cast<const float4*>(in)[i];
  short4v o;
  o[0] = f2bf(v.x); o[1] = f2bf(v.y); o[2] = f2bf(v.z); o[3] = f2bf(v.w);
  reinterpret_cast<short4v*>(out)[i] = o;
}

// ---------------- concat 5 weight matrices into (1280,1024) bf16 ----------------
__global__ __launch_bounds__(256) void k_pack_wcat(const float* __restrict__ qs,
    const float* __restrict__ ks, const float* __restrict__ qg, const float* __restrict__ kg,
    const float* __restrict__ vw, __hip_bfloat16* __restrict__ w, int n4) {
  int i = blockIdx.x * blockDim.x + threadIdx.x;
  if (i >= n4) return;
  int idx = i * 4;
  int row = idx >> 10;
  int col = idx & 1023;
  const float* src;
  if (row < 128)      src = qs + (size_t)row * DM;
  else if (row < 256) src = ks + (size_t)(row - 128) * DM;
  else if (row < 512) src = qg + (size_t)(row - 256) * DM;
  else if (row < 768) src = kg + (size_t)(row - 512) * DM;
  else                src = vw + (size_t)(row - 768) * DM;
  float4 v = *reinterpret_cast<const float4*>(src + col);
  short4v o;
  o[0] = f2bf(v.x); o[1] = f2bf(v.y); o[2] = f2bf(v.z); o[3] = f2bf(v.w);
  *reinterpret_cast<short4v*>(w + idx) = o;
}

// ---------------- bf16 GEMM, B^T layout: C[m][n] = sum_k A[m][k]*B[n][k] ----------------
template<int OUT_BF16>
__global__ __launch_bounds__(256) void k_gemm_bt(const __hip_bfloat16* __restrict__ A,
    const __hip_bfloat16* __restrict__ B, void* __restrict__ Cv, int M, int N, int K) {
  __shared__ alignas(16) __hip_bfloat16 lA[128 * 32];
  __shared__ alignas(16) __hip_bfloat16 lB[128 * 32];
  const int tid = threadIdx.x;
  const int lane = tid & 63;
  const int wid = tid >> 6;
  const int m0 = blockIdx.x * 128, n0 = blockIdx.y * 128;
  const int wm = (wid >> 1) * 64, wn = (wid & 1) * 64;
  const int srow = tid >> 2;          // 0..63
  const int scol = (tid & 3) * 8;     // bf16 elements
  const int fr = lane & 15, fk = (lane >> 4) * 8;
  f32x4 acc[4][4];
  const f32x4 zz = {0.f, 0.f, 0.f, 0.f};
#pragma unroll
  for (int m = 0; m < 4; ++m)
#pragma unroll
    for (int n = 0; n < 4; ++n) acc[m][n] = zz;

  for (int kt = 0; kt < K; kt += 32) {
    __syncthreads();
    {
      const __hip_bfloat16* ga0 = A + (size_t)(m0 + srow) * K + kt + scol;
      const __hip_bfloat16* ga1 = A + (size_t)(m0 + 64 + srow) * K + kt + scol;
      const __hip_bfloat16* gb0 = B + (size_t)(n0 + srow) * K + kt + scol;
      const __hip_bfloat16* gb1 = B + (size_t)(n0 + 64 + srow) * K + kt + scol;
      __builtin_amdgcn_global_load_lds((const __attribute__((address_space(1))) void*)ga0,
          (__attribute__((address_space(3))) void*)(lA + srow * 32 + scol), 16, 0, 0);
      __builtin_amdgcn_global_load_lds((const __attribute__((address_space(1))) void*)ga1,
          (__attribute__((address_space(3))) void*)(lA + (64 + srow) * 32 + scol), 16, 0, 0);
      __builtin_amdgcn_global_load_lds((const __attribute__((address_space(1))) void*)gb0,
          (__attribute__((address_space(3))) void*)(lB + srow * 32 + scol), 16, 0, 0);
      __builtin_amdgcn_global_load_lds((const __attribute__((address_space(1))) void*)gb1,
          (__attribute__((address_space(3))) void*)(lB + (64 + srow) * 32 + scol), 16, 0, 0);
    }
    __syncthreads();
    short8 af[4], bfr[4];
#pragma unroll
    for (int m = 0; m < 4; ++m)
      af[m] = *reinterpret_cast<const short8*>(lA + (wm + m * 16 + fr) * 32 + fk);
#pragma unroll
    for (int n = 0; n < 4; ++n)
      bfr[n] = *reinterpret_cast<const short8*>(lB + (wn + n * 16 + fr) * 32 + fk);
#pragma unroll
    for (int m = 0; m < 4; ++m)
#pragma unroll
      for (int n = 0; n < 4; ++n)
        acc[m][n] = __builtin_amdgcn_mfma_f32_16x16x32_bf16(af[m], bfr[n], acc[m][n], 0, 0, 0);
  }
  const int cr = (lane >> 4) * 4, cc = lane & 15;
#pragma unroll
  for (int m = 0; m < 4; ++m)
#pragma unroll
    for (int n = 0; n < 4; ++n)
#pragma unroll
      for (int j = 0; j < 4; ++j) {
        const int row = m0 + wm + m * 16 + cr + j;
        const int col = n0 + wn + n * 16 + cc;
        if (OUT_BF16)
          ((__hip_bfloat16*)Cv)[(size_t)row * N + col] = __float2bfloat16(acc[m][n][j]);
        else
          ((float*)Cv)[(size_t)row * N + col] = acc[m][n][j];
      }
}

// ---------------- RoPE + pack Q/K (H,T,32) and V^T (H,32,T) ----------------
// qscale folds 1/sqrt(24) * exp(logit_scale) * log2(e)  (softmax uses exp2)
__global__ __launch_bounds__(256) void k_rope_pack(const __hip_bfloat16* __restrict__ proj,
    const float* __restrict__ ls, const int* __restrict__ posp,
    __hip_bfloat16* __restrict__ Qp, __hip_bfloat16* __restrict__ Kp,
    __hip_bfloat16* __restrict__ Vt) {
  const int gid = blockIdx.x * blockDim.x + threadIdx.x;  // T*NH, t fastest
  const int t = gid & (TT - 1);
  const int h = gid >> 12;
  const __hip_bfloat16* pr = proj + (size_t)t * NPROJ;
  const float qscale = 0.20412414523193154f * 1.4426950408889634f * __expf(ls[h]);
  const float pos = (float)(t + posp[0]);
  const float invf[8] = {1.0f, 0.31622776601683794f, 0.1f, 0.031622776601683794f,
                         0.01f, 0.0031622776601683794f, 0.001f, 0.00031622776601683794f};
  short8 qv[4], kv[4];
  const short8 z8 = {0, 0, 0, 0, 0, 0, 0, 0};
  qv[3] = z8; kv[3] = z8;
#pragma unroll
  for (int i = 0; i < 8; ++i) {
    qv[0][i] = f2bf(bf2f(pr[h * 8 + i]) * qscale);
    kv[0][i] = f2bf(bf2f(pr[128 + h * 8 + i]));
  }
#pragma unroll
  for (int i = 0; i < 8; ++i) {
    const float ang = pos * invf[i];
    float ss, cc;
    __sincosf(ang, &ss, &cc);
    const float x1q = bf2f(pr[256 + h * 16 + i]), x2q = bf2f(pr[256 + h * 16 + 8 + i]);
    const float x1k = bf2f(pr[512 + h * 16 + i]), x2k = bf2f(pr[512 + h * 16 + 8 + i]);
    qv[1][i] = f2bf((x1q * cc - x2q * ss) * qscale);
    qv[2][i] = f2bf((x1q * ss + x2q * cc) * qscale);
    kv[1][i] = f2bf(x1k * cc - x2k * ss);
    kv[2][i] = f2bf(x1k * ss + x2k * cc);
  }
  short8* qdst = reinterpret_cast<short8*>(Qp + ((size_t)h * TT + t) * 32);
  short8* kdst = reinterpret_cast<short8*>(Kp + ((size_t)h * TT + t) * 32);
#pragma unroll
  for (int p = 0; p < 4; ++p) { qdst[p] = qv[p]; kdst[p] = kv[p]; }
#pragma unroll
  for (int i = 0; i < 32; ++i)
    Vt[((size_t)h * 32 + i) * TT + t] = pr[768 + h * 32 + i];
}

// ---------------- causal flash attention, LDS-shared K/V, LPT dispatch ----------------
// 1024 blocks x 4 waves; block = one (head, 64-row q-block). qb DESCENDS with
// blockIdx (longest-processing-time-first): long blocks dispatch first, short
// ones backfill -> tail bounded while 4 blocks/CU give 16 waves/CU latency hiding.
// LDS layouts = exact read order (every ds_read is base + lane*16, conflict-free);
// staging inverse-permutes the GLOBAL source per lane (rule #21):
//   K:  LDS[ct][g][c] 16B  <- K[kv=ct*16+c][8g..8g+8)
//   V:  LDS[kvb][db][g][c] 16B <- V^T[d=db*16+c][kvb*32+8g..+8)
__global__ __launch_bounds__(256) void k_attn(const __hip_bfloat16* __restrict__ Qp,
    const __hip_bfloat16* __restrict__ Kp, const __hip_bfloat16* __restrict__ Vt,
    __hip_bfloat16* __restrict__ Ob) {
  __shared__ alignas(16) __hip_bfloat16 lK[2][64 * 32];   // 4KB each
  __shared__ alignas(16) __hip_bfloat16 lV[2][32 * 64];   // 4KB each
  __shared__ alignas(16) __hip_bfloat16 Plds[4][16][72];
  const int lin = blockIdx.x;           // 0..1023
  const int xcd = lin & 7;
  const int idx = lin >> 3;             // 0..127
  const int h = xcd * 2 + (idx & 1);    // 2 heads per XCD
  const int qb = 63 - (idx >> 1);       // DESCENDING: big blocks first (LPT)
  const int nt = qb + 1;
  const int tid = threadIdx.x;
  const int lane = tid & 63, w = tid >> 6;
  const int g = lane >> 4, c = lane & 15;
  // staging source mapping (inverse of the LDS read permutation)
  const int krow = (tid >> 6) * 16 + (tid & 15);           // kv row within tile
  const int kcol = ((tid >> 4) & 3) * 8;                   // dim slot
  const int vrow = ((tid >> 6) & 1) * 16 + (tid & 15);     // d row
  const int vcol = ((tid >> 7) & 1) * 32 + ((tid >> 4) & 3) * 8;  // kv slot within tile
  const __hip_bfloat16* Kh = Kp + (size_t)h * TT * 32 + (size_t)krow * 32 + kcol;
  const __hip_bfloat16* Vh = Vt + (size_t)h * 32 * TT + (size_t)vrow * TT + vcol;
  const f32x4 zz = {0.f, 0.f, 0.f, 0.f};

  const int qrow = qb * 64 + w * 16 + c;
  const short8 qf =
      *reinterpret_cast<const short8*>(Qp + ((size_t)h * TT + qrow) * 32 + 8 * g);
  f32x4 o0 = zz, o1 = zz;
  float mst = -1e30f, lsum = 0.f;
  int cur = 0;
  // prologue: stage tile 0 into buf 0
  __builtin_amdgcn_global_load_lds(
      (const __attribute__((address_space(1))) void*)Kh,
      (__attribute__((address_space(3))) void*)(lK[0] + tid * 8), 16, 0, 0);
  __builtin_amdgcn_global_load_lds(
      (const __attribute__((address_space(1))) void*)Vh,
      (__attribute__((address_space(3))) void*)(lV[0] + tid * 8), 16, 0, 0);

  for (int it = 0; it < nt; ++it) {
    __syncthreads();  // buf[cur] staged + all waves done with buf[cur^1]
    if (it + 1 < nt) {
      const int kv1 = (it + 1) * 64;
      __builtin_amdgcn_global_load_lds(
          (const __attribute__((address_space(1))) void*)(Kh + (size_t)kv1 * 32),
          (__attribute__((address_space(3))) void*)(lK[cur ^ 1] + tid * 8), 16, 0, 0);
      __builtin_amdgcn_global_load_lds(
          (const __attribute__((address_space(1))) void*)(Vh + kv1),
          (__attribute__((address_space(3))) void*)(lV[cur ^ 1] + tid * 8), 16, 0, 0);
    }
    // K fragments: addr = base + lane*16 (conflict-free)
    const char* kb = (const char*)lK[cur];
    short8 kf[4];
#pragma unroll
    for (int ct = 0; ct < 4; ++ct)
      kf[ct] = *reinterpret_cast<const short8*>(kb + ct * 1024 + lane * 16);
    // V fragments: addr = base + lane*16 (conflict-free)
    const char* vb = (const char*)lV[cur];
    const short8 v00 = *reinterpret_cast<const short8*>(vb + lane * 16);
    const short8 v10 = *reinterpret_cast<const short8*>(vb + 1024 + lane * 16);
    const short8 v01 = *reinterpret_cast<const short8*>(vb + 2048 + lane * 16);
    const short8 v11 = *reinterpret_cast<const short8*>(vb + 3072 + lane * 16);
    f32x4 s[4];
#pragma unroll
    for (int ct = 0; ct < 4; ++ct)
      s[ct] = __builtin_amdgcn_mfma_f32_16x16x32_bf16(kf[ct], qf, zz, 0, 0, 0);  // swapped
    if (it == nt - 1) {  // diagonal tile: mask k > q
#pragma unroll
      for (int ct = 0; ct < 4; ++ct)
#pragma unroll
        for (int j = 0; j < 4; ++j)
          if (ct * 16 + g * 4 + j > w * 16 + c) s[ct][j] = -1e30f;
    }
    // in-lane max over 16 scores
    float m01 = fmaxf(fmaxf(s[0][0], s[0][1]), fmaxf(s[0][2], s[0][3]));
    float m23 = fmaxf(fmaxf(s[1][0], s[1][1]), fmaxf(s[1][2], s[1][3]));
    float m45 = fmaxf(fmaxf(s[2][0], s[2][1]), fmaxf(s[2][2], s[2][3]));
    float m67 = fmaxf(fmaxf(s[3][0], s[3][1]), fmaxf(s[3][2], s[3][3]));
    float pm_ = fmaxf(fmaxf(m01, m23), fmaxf(m45, m67));
    if (__any(pm_ > mst + 8.0f)) {  // defer-max
      float pm2 = fmaxf(pm_, __shfl_xor(pm_, 16, 64));
      pm2 = fmaxf(pm2, __shfl_xor(pm2, 32, 64));
      const float nm = fmaxf(mst, pm2);
      const float alpha = exp2f(mst - nm);
      mst = nm;
      lsum *= alpha;
#pragma unroll
      for (int j = 0; j < 4; ++j) { o0[j] *= alpha; o1[j] *= alpha; }
    }
    float ts = 0.f;
#pragma unroll
    for (int ct = 0; ct < 4; ++ct) {
#pragma unroll
      for (int j = 0; j < 4; ++j) s[ct][j] = exp2f(s[ct][j] - mst);
      ts += (s[ct][0] + s[ct][1]) + (s[ct][2] + s[ct][3]);
    }
    lsum += ts;
    // P -> LDS (packed bf16 pairs), per-wave private slice (2-way max: free)
#pragma unroll
    for (int ct = 0; ct < 4; ++ct) {
      float2 p01; p01.x = s[ct][0]; p01.y = s[ct][1];
      float2 p23; p23.x = s[ct][2]; p23.y = s[ct][3];
      __hip_bfloat162 b01 = __float22bfloat162_rn(p01);
      __hip_bfloat162 b23 = __float22bfloat162_rn(p23);
      *reinterpret_cast<__hip_bfloat162*>(&Plds[w][c][ct * 16 + g * 4]) = b01;
      *reinterpret_cast<__hip_bfloat162*>(&Plds[w][c][ct * 16 + g * 4 + 2]) = b23;
    }
    const short8 pf0 = *reinterpret_cast<const short8*>(&Plds[w][c][8 * g]);
    const short8 pf1 = *reinterpret_cast<const short8*>(&Plds[w][c][32 + 8 * g]);
    // O^T: C col = q-row = lane c
    o0 = __builtin_amdgcn_mfma_f32_16x16x32_bf16(v00, pf0, o0, 0, 0, 0);
    o0 = __builtin_amdgcn_mfma_f32_16x16x32_bf16(v01, pf1, o0, 0, 0, 0);
    o1 = __builtin_amdgcn_mfma_f32_16x16x32_bf16(v10, pf0, o1, 0, 0, 0);
    o1 = __builtin_amdgcn_mfma_f32_16x16x32_bf16(v11, pf1, o1, 0, 0, 0);
    cur ^= 1;
  }
  // final lsum reduce across g-lanes of row c; write Ob
  lsum += __shfl_xor(lsum, 16, 64);
  lsum += __shfl_xor(lsum, 32, 64);
  const float inv = 1.0f / lsum;
  __hip_bfloat16* dst = Ob + (size_t)qrow * DATTN + h * 32;
  short4v w0, w1;
#pragma unroll
  for (int j = 0; j < 4; ++j) { w0[j] = f2bf(o0[j] * inv); w1[j] = f2bf(o1[j] * inv); }
  *reinterpret_cast<short4v*>(dst + g * 4) = w0;
  *reinterpret_cast<short4v*>(dst + 16 + g * 4) = w1;
}

extern "C" void kernel_launch(void* const* d_in, const int* in_sizes, int n_in,
                              void* d_out, int out_size, void* d_ws, size_t ws_size,
                              hipStream_t stream) {
  const float* x   = (const float*)d_in[0];
  const float* qsw = (const float*)d_in[1];
  const float* ksw = (const float*)d_in[2];
  const float* qgw = (const float*)d_in[3];
  const float* kgw = (const float*)d_in[4];
  const float* vw  = (const float*)d_in[5];
  const float* ow  = (const float*)d_in[6];
  const float* ls  = (const float*)d_in[7];
  const int* posp  = (const int*)d_in[9];

  size_t off = 0;
  auto alloc = [&](size_t bytes) {
    char* p = (char*)d_ws + off;
    off += (bytes + 255) & ~(size_t)255;
    return (void*)p;
  };
  __hip_bfloat16* Xbf  = (__hip_bfloat16*)alloc((size_t)TT * DM * 2);
  __hip_bfloat16* Wcat = (__hip_bfloat16*)alloc((size_t)NPROJ * DM * 2);
  __hip_bfloat16* OW   = (__hip_bfloat16*)alloc((size_t)DM * DATTN * 2);
  __hip_bfloat16* proj = (__hip_bfloat16*)alloc((size_t)TT * NPROJ * 2);
  __hip_bfloat16* Qp   = (__hip_bfloat16*)alloc((size_t)NH * TT * 32 * 2);
  __hip_bfloat16* Kpk  = (__hip_bfloat16*)alloc((size_t)NH * TT * 32 * 2);
  __hip_bfloat16* Vt   = (__hip_bfloat16*)alloc((size_t)NH * 32 * TT * 2);
  __hip_bfloat16* Ob   = (__hip_bfloat16*)alloc((size_t)TT * DATTN * 2);

  k_f32_to_bf16<<<dim3((TT * DM / 4) / 256), 256, 0, stream>>>(x, Xbf, TT * DM / 4);
  k_f32_to_bf16<<<dim3((DM * DATTN / 4) / 256), 256, 0, stream>>>(ow, OW, DM * DATTN / 4);
  k_pack_wcat<<<dim3((NPROJ * DM / 4) / 256), 256, 0, stream>>>(qsw, ksw, qgw, kgw, vw, Wcat,
                                                                NPROJ * DM / 4);
  k_gemm_bt<1><<<dim3(TT / 128, NPROJ / 128), 256, 0, stream>>>(Xbf, Wcat, (void*)proj,
                                                                TT, NPROJ, DM);
  k_rope_pack<<<dim3(TT * NH / 256), 256, 0, stream>>>(proj, ls, posp, Qp, Kpk, Vt);
  k_attn<<<dim3(1024), 256, 0, stream>>>(Qp, Kpk, Vt, Ob);
  k_gemm_bt<0><<<dim3(TT / 128, DM / 128), 256, 0, stream>>>(Ob, OW, (void*)d_out,
                                                             TT, DM, DATTN);
}